// Round 16
// baseline (304.227 us; speedup 1.0000x reference)
//
#include <hip/hip_runtime.h>
#include <math.h>

#define NN 8192
#define REV_CAP 48
#define KNN_CAP 384   // per-wave survivor cap (E[survivors]~72; P(overflow) astronomically small)
#define PF 12         // k_msg edge-gather prefetch depth
#define NREP 32       // stats replica count (cuts atomic chains 2048 -> 64 deep)

// ---- ws layout (float element offsets) ----
static const size_t OFF_K     = 0;        // 405
static const size_t OFF_CNT   = 512;      // int[8192]
static const size_t OFF_REV   = 8704;     // int[8192*48] -> ends 401920
static const size_t OFF_STATS = 401920;   // 3 layers x (32 reps x 96 A | 32 reps x 96 B) = 3*6144
static const size_t OFF_XF    = 420480;   // 8192*120 interleaved features (16B aligned)
static const size_t OFF_YF    = 1403520;  // 8192*120 outputs (head aliased as SoA x/y/z/q for KNN)
static const size_t WS_FLOATS = 2386560;  // < 2499200 proven available

// =================== K tensor math (device, double precision) ===================
__device__ double dfact(int n){ double r=1.0; for(int i=2;i<=n;++i) r*=(double)i; return r; }

__device__ double dcg(int j1,int m1,int j2,int m2,int j3,int m3){
  if (m1+m2!=m3) return 0.0;
  if (j3 < abs(j1-j2) || j3 > j1+j2) return 0.0;
  double pre = sqrt((double)(2*j3+1)*dfact(j3+j1-j2)*dfact(j3-j1+j2)*dfact(j1+j2-j3)/dfact(j1+j2+j3+1));
  pre *= sqrt(dfact(j3+m3)*dfact(j3-m3)*dfact(j1-m1)*dfact(j1+m1)*dfact(j2-m2)*dfact(j2+m2));
  double s=0.0;
  for(int k=0;k<=j1+j2-j3;++k){
    int d1=j1+j2-j3-k, d2=j1-m1-k, d3=j2+m2-k, d4=j3-j2+m1+k, d5=j3-j1-m2+k;
    if(d1<0||d2<0||d3<0||d4<0||d5<0) continue;
    double den = dfact(k)*dfact(d1)*dfact(d2)*dfact(d3)*dfact(d4)*dfact(d5);
    s += ((k&1)? -1.0: 1.0)/den;
  }
  return pre*s;
}

__device__ int qrow(int l,int r,int* col,double* re,double* im){
  const double s = 0.70710678118654752440;
  if (r==l){ col[0]=l; re[0]=1.0; im[0]=0.0; return 1; }
  if (r>l){ int m=r-l;
    col[0]=l+m; re[0]=((m&1)?-s:s); im[0]=0.0;
    col[1]=l-m; re[1]=s;            im[1]=0.0;
  } else { int m=l-r;
    col[0]=l+m; re[0]=0.0; im[0]=((m&1)? s : -s);
    col[1]=l-m; re[1]=0.0; im[1]=s;
  }
  return 2;
}

// =================== fused setup: xf init | SoA+q | cnt | stats zero | K ===================
// virtual idx: [0,983040) xf | +8192 soa | +8192 cnt | +18432 stats | +405 K
__global__ __launch_bounds__(256) void k_setup(const float* __restrict__ pos,
        const float* __restrict__ W_emb, float* __restrict__ Kbuf,
        float* __restrict__ xf,
        float* __restrict__ xs, float* __restrict__ ys, float* __restrict__ zs,
        float* __restrict__ qs,
        int* __restrict__ cnt, float* __restrict__ stats){
  int idx = blockIdx.x*256 + threadIdx.x;
  if (idx < 983040) { const int c = idx%120; xf[idx] = (c<32)? W_emb[c] : 0.f; return; }
  idx -= 983040;
  if (idx < 8192) {
    const float x=pos[3*idx], y=pos[3*idx+1], z=pos[3*idx+2];
    xs[idx]=x; ys[idx]=y; zs[idx]=z; qs[idx]=0.5f*(x*x+y*y+z*z);
    return;
  }
  idx -= 8192;
  if (idx < 8192) { cnt[idx]=0; return; }
  idx -= 8192;
  if (idx < 18432) { stats[idx]=0.f; return; }
  idx -= 18432;
  if (idx >= 405) return;

  const int tid = idx;
  const int sizes[9]={1,25,9,45,75,25,25,75,125};
  const int l1s[9]={0,0,1,1,1,2,2,2,2};
  const int l2s[9]={0,2,0,2,2,0,2,2,2};
  const int l3s[9]={0,2,1,1,2,2,0,1,2};
  int p=0, rem=tid;
  for(p=0;p<9;++p){ if(rem < sizes[p]) break; rem -= sizes[p]; }
  const int l1=l1s[p], l2=l2s[p], l3=l3s[p];
  const int n1=2*l1+1, n2=2*l2+1;
  const int c = rem/(n1*n2); const int r2 = rem%(n1*n2); const int a=r2/n2; const int b=r2%n2;

  int c3[2],c1[2],c2[2]; double re3[2],im3[2],re1[2],im1[2],re2[2],im2[2];
  const int nc3 = qrow(l3,c,c3,re3,im3);
  const int nc1 = qrow(l1,a,c1,re1,im1);
  const int nc2 = qrow(l2,b,c2,re2,im2);

  double accRe=0, accIm=0;
  for(int i3=0;i3<nc3;++i3){
    const double q3re=re3[i3], q3im=-im3[i3];
    for(int i1=0;i1<nc1;++i1){
      const double pre_re = q3re*re1[i1] - q3im*im1[i1];
      const double pre_im = q3re*im1[i1] + q3im*re1[i1];
      for(int i2=0;i2<nc2;++i2){
        const double cgv = dcg(l1, c1[i1]-l1, l2, c2[i2]-l2, l3, c3[i3]-l3);
        if (cgv==0.0) continue;
        accRe += (pre_re*re2[i2] - pre_im*im2[i2])*cgv;
        accIm += (pre_re*im2[i2] + pre_im*re2[i2])*cgv;
      }
    }
  }
  const bool useImag = ((l1+l2+l3)&1)!=0;
  Kbuf[tid] = (float)(useImag? accIm : accRe);
}

// =================== exact 9-NN (round-15 k_knn8 verbatim) ===================
__global__ __launch_bounds__(256) void k_knn8(const float* __restrict__ xs,
                                              const float* __restrict__ ys,
                                              const float* __restrict__ zs,
                                              const float* __restrict__ qs,
                                              int* __restrict__ cnt, int* __restrict__ rev){
  const int lane = threadIdx.x & 63;
  const int w    = threadIdx.x >> 6;
  const int node = blockIdx.x*4 + w;
  __shared__ float sdist[4][KNN_CAP];
  __shared__ int   sidx[4][KNN_CAP];
  __shared__ int   scount[4];
  if (threadIdx.x < 4) scount[threadIdx.x]=0;
  __syncthreads();

  const float px = xs[node], py = ys[node], pz = zs[node];

  float m1 = INFINITY, m2 = INFINITY;
  for(int c=0;c<4;++c){
    const int base = (c*64 + lane)*4;
    const float4 fx = *(const float4*)(xs + base);
    const float4 fy = *(const float4*)(ys + base);
    const float4 fz = *(const float4*)(zs + base);
    const float4 fq = *(const float4*)(qs + base);
    float ss[4];
    ss[0] = fmaf(-px,fx.x, fmaf(-py,fy.x, fmaf(-pz,fz.x, fq.x)));
    ss[1] = fmaf(-px,fx.y, fmaf(-py,fy.y, fmaf(-pz,fz.y, fq.y)));
    ss[2] = fmaf(-px,fx.z, fmaf(-py,fy.z, fmaf(-pz,fz.z, fq.z)));
    ss[3] = fmaf(-px,fx.w, fmaf(-py,fy.w, fmaf(-pz,fz.w, fq.w)));
    #pragma unroll
    for(int q=0;q<4;++q){
      const float hi = fmaxf(m1, ss[q]);
      m1 = fminf(m1, ss[q]);
      m2 = fminf(m2, hi);
    }
  }
  float T = INFINITY;
  for(int r=0;r<9;++r){
    float v = m1; int l = lane;
    #pragma unroll
    for(int s=32;s>0;s>>=1){
      const float ov=__shfl_xor(v,s,64); const int ol=__shfl_xor(l,s,64);
      if (ov<v || (ov==v && ol<l)){ v=ov; l=ol; }
    }
    T = v;
    if (lane==l){ m1=m2; m2=INFINITY; }
  }

  for(int c=0;c<32;++c){
    const int base = (c*64 + lane)*4;
    const float4 fx = *(const float4*)(xs + base);
    const float4 fy = *(const float4*)(ys + base);
    const float4 fz = *(const float4*)(zs + base);
    const float4 fq = *(const float4*)(qs + base);
    float ss[4];
    ss[0] = fmaf(-px,fx.x, fmaf(-py,fy.x, fmaf(-pz,fz.x, fq.x)));
    ss[1] = fmaf(-px,fx.y, fmaf(-py,fy.y, fmaf(-pz,fz.y, fq.y)));
    ss[2] = fmaf(-px,fx.z, fmaf(-py,fy.z, fmaf(-pz,fz.z, fq.z)));
    ss[3] = fmaf(-px,fx.w, fmaf(-py,fy.w, fmaf(-pz,fz.w, fq.w)));
    #pragma unroll
    for(int q=0;q<4;++q){
      if (ss[q] <= T){
        int pos = atomicAdd(&scount[w],1);
        if (pos < KNN_CAP){ sdist[w][pos]=ss[q]; sidx[w][pos]=base+q; }
      }
    }
  }
  __syncthreads();

  int m = scount[w]; if (m > KNN_CAP) m = KNN_CAP;
  float dl[KNN_CAP/64]; int il[KNN_CAP/64];
  #pragma unroll
  for(int k=0;k<KNN_CAP/64;++k){
    const int j = lane + 64*k;
    if (j < m){ dl[k]=sdist[w][j]; il[k]=sidx[w][j]; }
    else      { dl[k]=INFINITY;    il[k]=0x7fffffff; }
  }
  for(int r=0;r<9;++r){
    float bv=dl[0]; int bi=il[0];
    #pragma unroll
    for(int k=1;k<KNN_CAP/64;++k){
      if (dl[k]<bv || (dl[k]==bv && il[k]<bi)){ bv=dl[k]; bi=il[k]; }
    }
    float v=bv; int ix=bi;
    #pragma unroll
    for(int s=32;s>0;s>>=1){
      float ov=__shfl_xor(v,s,64); int oi=__shfl_xor(ix,s,64);
      if (ov<v || (ov==v && oi<ix)){ v=ov; ix=oi; }
    }
    if (ix != node && lane==0){
      int cpos = atomicAdd(&cnt[ix],1);
      if (cpos < REV_CAP) rev[ix*REV_CAP + cpos] = node;
    }
    #pragma unroll
    for(int k=0;k<KNN_CAP/64;++k){
      if (il[k]==ix){ dl[k]=INFINITY; il[k]=0x7fffffff; }
    }
  }
}

// =================== moment-based message passing + fused replicated stats ===================
// r15 proven body; epilogue accumulates block-level stats in LDS (ds_add_f32), then
// flushes 192 global atomics into replica (blockIdx & 31) -> 64-deep chains, not 2048.
__global__ __launch_bounds__(256) void k_msg(
  const float* __restrict__ pos,
  const int* __restrict__ cnt, const int* __restrict__ rev,
  const float* __restrict__ Kbuf,
  const float* __restrict__ xf,
  const float* __restrict__ tpw,
  const float* __restrict__ W0, const float* __restrict__ W1, const float* __restrict__ W2,
  float* __restrict__ yf,
  float* __restrict__ statsA, float* __restrict__ statsB)
{
  const int t = threadIdx.x;
  const int w = t >> 6;
  const int lane = t & 63;
  const int n = blockIdx.x*4 + w;

  __shared__ float KL[405];
  __shared__ float TW[144];
  __shared__ float momP[4][120];
  __shared__ float momS[4][600];
  __shared__ float aS[4][480];
  __shared__ int   eIdx[4][REV_CAP];
  __shared__ float eSh[4][5][REV_CAP];
  __shared__ float sA[96], sB[96];
  for(int q=t;q<405;q+=256) KL[q]=Kbuf[q];
  for(int q=t;q<144;q+=256) TW[q]=tpw[q];
  if (t<96){ sA[t]=0.f; sB[t]=0.f; }

  // Stage 1a: parallel edge geometry (lane e < deg owns edge e)
  const int deg0 = cnt[n];
  const int deg = (deg0<REV_CAP)? deg0 : REV_CAP;
  const float pnx=pos[3*n], pny=pos[3*n+1], pnz=pos[3*n+2];
  const float s15 = 3.8729833462f, s5c = 2.2360679775f;
  if (lane < deg){
    const int i = rev[n*REV_CAP+lane];
    eIdx[w][lane] = i;
    const float ex = pnx - pos[3*i], ey = pny - pos[3*i+1], ez = pnz - pos[3*i+2];
    const float rn = sqrtf(ex*ex+ey*ey+ez*ez) + 1e-12f;
    const float ux=ex/rn, uy=ey/rn, uz=ez/rn;
    eSh[w][0][lane]=s15*ux*uy;
    eSh[w][1][lane]=s15*uy*uz;
    eSh[w][2][lane]=0.5f*s5c*(3.f*uz*uz-1.f);
    eSh[w][3][lane]=s15*ux*uz;
    eSh[w][4][lane]=0.5f*s15*(ux*ux-uy*uy);
  }
  __syncthreads();

  // Stage 1b: moment accumulation with prefetched gathers
  const int c0 = lane*2;
  float mp0=0.f, mp1=0.f;
  float ms0[5], ms1[5];
  #pragma unroll
  for(int j=0;j<5;++j){ ms0[j]=0.f; ms1[j]=0.f; }

  int idxr[PF];
  #pragma unroll
  for(int k=0;k<PF;++k) idxr[k] = (k<deg)? eIdx[w][k] : 0;
  float2 fr[PF];
  if (lane<60){
    #pragma unroll
    for(int k=0;k<PF;++k) fr[k] = *(const float2*)(xf + (size_t)idxr[k]*120 + c0);
  }
  #pragma unroll
  for(int k=0;k<PF;++k){
    if (k<deg){
      const float sh0=eSh[w][0][k], sh1=eSh[w][1][k], sh2=eSh[w][2][k];
      const float sh3=eSh[w][3][k], sh4=eSh[w][4][k];
      if (lane<60){
        const float2 f = fr[k];
        mp0 += f.x; mp1 += f.y;
        ms0[0]+=f.x*sh0; ms0[1]+=f.x*sh1; ms0[2]+=f.x*sh2; ms0[3]+=f.x*sh3; ms0[4]+=f.x*sh4;
        ms1[0]+=f.y*sh0; ms1[1]+=f.y*sh1; ms1[2]+=f.y*sh2; ms1[3]+=f.y*sh3; ms1[4]+=f.y*sh4;
      }
    }
  }
  for(int e=PF;e<deg;++e){   // rare tail (deg>PF)
    const int i = eIdx[w][e];
    const float sh0=eSh[w][0][e], sh1=eSh[w][1][e], sh2=eSh[w][2][e];
    const float sh3=eSh[w][3][e], sh4=eSh[w][4][e];
    if (lane<60){
      const float2 f = *(const float2*)(xf + (size_t)i*120 + c0);
      mp0 += f.x; mp1 += f.y;
      ms0[0]+=f.x*sh0; ms0[1]+=f.x*sh1; ms0[2]+=f.x*sh2; ms0[3]+=f.x*sh3; ms0[4]+=f.x*sh4;
      ms1[0]+=f.y*sh0; ms1[1]+=f.y*sh1; ms1[2]+=f.y*sh2; ms1[3]+=f.y*sh3; ms1[4]+=f.y*sh4;
    }
  }
  if (lane<60){
    momP[w][c0]=mp0; momP[w][c0+1]=mp1;
    #pragma unroll
    for(int j=0;j<5;++j){ momS[w][c0*5+j]=ms0[j]; momS[w][(c0+1)*5+j]=ms1[j]; }
  }
  __syncthreads();

  // Stage 2: per-node K-contraction on moments
  float acc[14];
  #pragma unroll
  for(int k=0;k<14;++k) acc[k]=0.f;

  if (lane<32){
    const int u=lane;
    const float rw0=TW[u], rw1=TW[32+u];
    acc[0] = rw0 * KL[0] * momP[w][u];                       // p1
    float m0s[5];
    #pragma unroll
    for(int j=0;j<5;++j) m0s[j]=momS[w][u*5+j];
    #pragma unroll
    for(int o=0;o<5;++o){ float g=0.f;                       // p2
      #pragma unroll
      for(int j=0;j<5;++j) g += KL[1+o*5+j]*m0s[j];
      acc[1+o] = rw1*g; }
  } else if (lane<48){
    const int u=lane-32;
    const float rw0=TW[64+u], rw1=TW[80+u], rw2=TW[96+u];
    float m1p[3], m1s[3][5];
    #pragma unroll
    for(int i=0;i<3;++i){
      m1p[i]=momP[w][32+u*3+i];
      #pragma unroll
      for(int j=0;j<5;++j) m1s[i][j]=momS[w][(32+u*3+i)*5+j];
    }
    #pragma unroll
    for(int o=0;o<3;++o){ float g=0.f;                       // p3
      #pragma unroll
      for(int i=0;i<3;++i) g += KL[26+o*3+i]*m1p[i];
      acc[o]=rw0*g; }
    #pragma unroll
    for(int o=0;o<3;++o){ float g=0.f;                       // p4
      #pragma unroll
      for(int i=0;i<3;++i)
        #pragma unroll
        for(int j=0;j<5;++j) g += KL[35+(o*3+i)*5+j]*m1s[i][j];
      acc[3+o]=rw1*g; }
    #pragma unroll
    for(int o=0;o<5;++o){ float g=0.f;                       // p5
      #pragma unroll
      for(int i=0;i<3;++i)
        #pragma unroll
        for(int j=0;j<5;++j) g += KL[80+(o*3+i)*5+j]*m1s[i][j];
      acc[6+o]=rw2*g; }
  } else if (lane<56){
    const int u=lane-48;
    const float rw0=TW[112+u], rw1=TW[120+u], rw2=TW[128+u], rw3=TW[136+u];
    float m2p[5], m2s[5][5];
    #pragma unroll
    for(int i=0;i<5;++i){
      m2p[i]=momP[w][80+u*5+i];
      #pragma unroll
      for(int j=0;j<5;++j) m2s[i][j]=momS[w][(80+u*5+i)*5+j];
    }
    #pragma unroll
    for(int o=0;o<5;++o){ float g=0.f;                       // p6
      #pragma unroll
      for(int i=0;i<5;++i) g += KL[155+o*5+i]*m2p[i];
      acc[o]=rw0*g; }
    { float g=0.f;                                           // p7
      #pragma unroll
      for(int i=0;i<5;++i)
        #pragma unroll
        for(int j=0;j<5;++j) g += KL[180+i*5+j]*m2s[i][j];
      acc[5]=rw1*g; }
    #pragma unroll
    for(int o=0;o<3;++o){ float g=0.f;                       // p8
      #pragma unroll
      for(int i=0;i<5;++i)
        #pragma unroll
        for(int j=0;j<5;++j) g += KL[205+(o*5+i)*5+j]*m2s[i][j];
      acc[6+o]=rw2*g; }
    #pragma unroll
    for(int o=0;o<5;++o){ float g=0.f;                       // p9
      #pragma unroll
      for(int i=0;i<5;++i)
        #pragma unroll
        for(int j=0;j<5;++j) g += KL[280+(o*5+i)*5+j]*m2s[i][j];
      acc[9+o]=rw3*g; }
  }

  // scatter into aS: concat m0=[p1,p7], m1=[p3,p4,p8], m2=[p2,p5,p6,p9]
  if (lane<32){
    aS[w][lane] = acc[0];
    #pragma unroll
    for(int o=0;o<5;++o) aS[w][160 + lane*5+o] = acc[1+o];
  } else if (lane<48){
    const int uu=lane-32;
    #pragma unroll
    for(int m=0;m<3;++m){ aS[w][40 + uu*3+m] = acc[m]; aS[w][40 + (16+uu)*3+m] = acc[3+m]; }
    #pragma unroll
    for(int o=0;o<5;++o) aS[w][160 + (32+uu)*5+o] = acc[6+o];
  } else if (lane<56){
    const int uu=lane-48;
    aS[w][32+uu] = acc[5];
    #pragma unroll
    for(int m=0;m<3;++m) aS[w][40 + (32+uu)*3+m] = acc[6+m];
    #pragma unroll
    for(int o=0;o<5;++o){ aS[w][160 + (48+uu)*5+o] = acc[o]; aS[w][160 + (56+uu)*5+o] = acc[9+o]; }
  }
  __syncthreads();

  // Stage 3: linear mixes, write yf[n][120], accumulate block stats in LDS
  const float inv40 = 0.15811388300841896660f;
  for(int q=lane;q<120;q+=64){
    float out;
    int chan;
    if (q<32){
      float g=0.f;
      for(int uu=0;uu<40;++uu) g += aS[w][uu]*W0[uu*32+q];
      out = g*inv40;
      chan = q;
      atomicAdd(&sA[q], out);
    } else if (q<80){
      const int e=q-32, v=e/3, m=e%3;
      float g=0.f;
      for(int uu=0;uu<40;++uu) g += aS[w][40+uu*3+m]*W1[uu*16+v];
      out = g*inv40;
      chan = 32+v;
    } else {
      const int e=q-80, tt=e/5, m=e%5;
      float g=0.f;
      for(int uu=0;uu<64;++uu) g += aS[w][160+uu*5+m]*W2[uu*8+tt];
      out = g*0.125f;
      chan = 48+tt;
    }
    atomicAdd(&sB[chan], out*out);
    yf[(size_t)n*120+q] = out;
  }
  __syncthreads();

  // flush block stats to replica (blockIdx & 31)
  if (t<96){
    const int rep = blockIdx.x & (NREP-1);
    if (t<32) atomicAdd(&statsA[rep*96+t], sA[t]);
    atomicAdd(&statsB[rep*96+t], sB[t]);
  }
}

// =================== normalize + relu + residual (layers 0,1): sum replicas + apply ===================
__global__ __launch_bounds__(256) void k_norm(const float* __restrict__ yf,
                       const float* __restrict__ statsA, const float* __restrict__ statsB,
                       const float* __restrict__ bw0,const float* __restrict__ bb0,
                       const float* __restrict__ bw1,const float* __restrict__ bw2,
                       float* __restrict__ xf){
  __shared__ float sc[96], sf[32];
  const int t = threadIdx.x;
  if (t<96){
    float sB=0.f;
    #pragma unroll 8
    for(int r=0;r<NREP;++r) sB += statsB[r*96+t];
    float scale;
    if (t<32){
      float sA=0.f;
      #pragma unroll 8
      for(int r=0;r<NREP;++r) sA += statsA[r*96+t];
      const float mean = sA*(1.f/8192.f);
      const float var  = sB*(1.f/8192.f) - mean*mean;
      const float inv  = 1.f/sqrtf(var+1e-5f);
      scale = bw0[t]*inv;
      sf[t] = bb0[t] - mean*scale;
    } else if (t<48){
      scale = bw1[t-32]/sqrtf(sB*(1.f/(8192.f*3.f))+1e-5f);
    } else {
      scale = bw2[t-48]/sqrtf(sB*(1.f/(8192.f*5.f))+1e-5f);
    }
    sc[t]=scale;
  }
  __syncthreads();
  const int idx = blockIdx.x*256 + t;
  if (idx >= NN*120) return;
  const int c = idx%120;
  const int chan = (c<32)? c : ((c<80)? 32+(c-32)/3 : 48+(c-80)/5);
  const float v = yf[idx]*sc[chan] + ((c<32)? sf[c] : 0.f);
  xf[idx] += fmaxf(v,0.f);
}

// =================== fused layer-3 norm (x0 only; l1/l2 dead) + final MLP ===================
__global__ __launch_bounds__(256) void k_normmlp(const float* __restrict__ yf,
                                             const float* __restrict__ xf,
                                             const float* __restrict__ statsA, const float* __restrict__ statsB,
                                             const float* __restrict__ bw0,const float* __restrict__ bb0,
                                             const float* __restrict__ Wf1,const float* __restrict__ Wf2,
                                             const float* __restrict__ bf2,const float* __restrict__ Wf3,
                                             const float* __restrict__ bf3, float* __restrict__ out){
  __shared__ float w1[1024], w2[512], w3[32], b2[16], b3[2], sc0[32], sf0[32];
  const int t=threadIdx.x;
  for(int q=t;q<1024;q+=256) w1[q]=Wf1[q];
  for(int q=t;q<512;q+=256)  w2[q]=Wf2[q];
  if(t<32) w3[t]=Wf3[t];
  if(t<16) b2[t]=bf2[t];
  if(t<2)  b3[t]=bf3[t];
  if(t<32){
    float sA=0.f, sB=0.f;
    #pragma unroll 8
    for(int r=0;r<NREP;++r){ sA += statsA[r*96+t]; sB += statsB[r*96+t]; }
    const float mean = sA*(1.f/8192.f);
    const float var  = sB*(1.f/8192.f) - mean*mean;
    const float inv  = 1.f/sqrtf(var+1e-5f);
    sc0[t] = bw0[t]*inv;
    sf0[t] = bb0[t] - mean*sc0[t];
  }
  __syncthreads();
  const int n = blockIdx.x*256+t;
  if(n>=NN) return;
  float xv[32];
  #pragma unroll
  for(int k=0;k<32;++k){
    const float v = yf[(size_t)n*120+k]*sc0[k] + sf0[k];
    xv[k] = xf[(size_t)n*120+k] + fmaxf(v,0.f);
  }
  const float inv32 = 0.17677669529663688110f;
  float h1[32];
  #pragma unroll 4
  for(int c=0;c<32;++c){ float g=0.f;
    #pragma unroll
    for(int k=0;k<32;++k) g+=xv[k]*w1[k*32+c];
    h1[c]=fmaxf(g*inv32,0.f); }
  float h2[16];
  #pragma unroll 4
  for(int c=0;c<16;++c){ float g=b2[c];
    #pragma unroll
    for(int k=0;k<32;++k) g+=h1[k]*w2[k*16+c];
    h2[c]=fmaxf(g,0.f); }
  #pragma unroll
  for(int m=0;m<2;++m){ float g=b3[m];
    #pragma unroll
    for(int k=0;k<16;++k) g+=h2[k]*w3[k*2+m];
    out[n*2+m]=g; }
}

extern "C" void kernel_launch(void* const* d_in, const int* in_sizes, int n_in,
                              void* d_out, int out_size, void* d_ws, size_t ws_size,
                              hipStream_t stream) {
  const float* positions = (const float*)d_in[0];
  const float* W_emb  = (const float*)d_in[1];
  const float* tp_w   = (const float*)d_in[2];
  const float* lin_W0 = (const float*)d_in[3];
  const float* lin_W1 = (const float*)d_in[4];
  const float* lin_W2 = (const float*)d_in[5];
  const float* bn_w0  = (const float*)d_in[6];
  const float* bn_b0  = (const float*)d_in[7];
  const float* bn_w1  = (const float*)d_in[8];
  const float* bn_w2  = (const float*)d_in[9];
  const float* Wf1 = (const float*)d_in[10];
  const float* Wf2 = (const float*)d_in[11];
  const float* bf2 = (const float*)d_in[12];
  const float* Wf3 = (const float*)d_in[13];
  const float* bf3 = (const float*)d_in[14];

  if (ws_size < WS_FLOATS*sizeof(float)) return;

  float* ws    = (float*)d_ws;
  float* Kbuf  = ws + OFF_K;
  int*   cnt   = (int*)(ws + OFF_CNT);
  int*   rev   = (int*)(ws + OFF_REV);
  float* stats = ws + OFF_STATS;   // 3 layers x (32x96 A | 32x96 B)
  float* xf = ws + OFF_XF;
  float* yf = ws + OFF_YF;

  // SoA position arrays alias the head of yf (dead after k_knn8; first k_msg rewrites yf)
  float* xs = yf;
  float* ysA = yf + NN;
  float* zs = yf + 2*NN;
  float* qs = yf + 3*NN;

  // setup virtual space: 983040 + 8192 + 8192 + 18432 + 405 = 1018261 -> 3978 blocks
  k_setup<<<3978,256,0,stream>>>(positions, W_emb, Kbuf, xf, xs, ysA, zs, qs, cnt, stats);
  k_knn8<<<NN/4,256,0,stream>>>(xs, ysA, zs, qs, cnt, rev);

  for(int l=0;l<3;++l){
    float* sAb = stats + l*6144;
    float* sBb = sAb + 3072;
    k_msg<<<NN/4,256,0,stream>>>(positions, cnt, rev, Kbuf, xf,
                              tp_w + l*144, lin_W0 + l*40*32, lin_W1 + l*40*16, lin_W2 + l*64*8,
                              yf, sAb, sBb);
    if (l<2){
      k_norm<<<(NN*120+255)/256,256,0,stream>>>(yf, sAb, sBb,
                              bn_w0 + l*32, bn_b0 + l*32, bn_w1 + l*16, bn_w2 + l*8,
                              xf);
    }
  }
  k_normmlp<<<NN/256,256,0,stream>>>(yf, xf, stats + 2*6144, stats + 2*6144 + 3072,
                              bn_w0 + 64, bn_b0 + 64,
                              Wf1, Wf2, bf2, Wf3, bf3, (float*)d_out);
}